// Round 15
// baseline (204.878 us; speedup 1.0000x reference)
//
#include <hip/hip_runtime.h>

typedef __bf16 bf16x8 __attribute__((ext_vector_type(8)));
typedef __bf16 bf16x4 __attribute__((ext_vector_type(4)));
typedef float f32x16 __attribute__((ext_vector_type(16)));
typedef float f32x4 __attribute__((ext_vector_type(4)));

constexpr int S = 128, R = 256, CM = 256, C = 32, CZ = 128;

#define MFMA __builtin_amdgcn_mfma_f32_32x32x16_bf16

__device__ __forceinline__ bf16x4 cvt4(float a, float b, float c, float d) {
    bf16x4 r;
    r[0] = (__bf16)a; r[1] = (__bf16)b; r[2] = (__bf16)c; r[3] = (__bf16)d;
    return r;
}

// K0: merged prep. blocks 0..511: WTf[((k>>3)*128+cz)*8+(k&7)] = bf16(W[(c*32+e)*128+cz]);
// blocks 512..575: WLRT[c][m] from left/right.
__global__ __launch_bounds__(256) void k_prep(const float* __restrict__ W,
                                              const float* __restrict__ Lp,
                                              const float* __restrict__ Rp,
                                              __bf16* __restrict__ WTf,
                                              __bf16* __restrict__ WLRT) {
    int b = blockIdx.x;
    if (b < 512) {
        int g = b * 256 + threadIdx.x;
        int cz = g & 127;
        int k = g >> 7;
        int e = k >> 5, c = k & 31;
        float v = W[(size_t)(c * 32 + e) * 128 + cz];
        WTf[((size_t)(k >> 3) * 128 + cz) * 8 + (k & 7)] = (__bf16)v;
    } else {
        int c = b - 512;
        int m = threadIdx.x;
        const float* src = (c < 32) ? Lp : Rp;
        WLRT[(size_t)c * 256 + m] = (__bf16)src[(size_t)m * 32 + (c & 31)];
    }
}

// K1: block (r, s-quarter=32 rows), 256 thr / 4 waves = (ksh x sd).
// K(m)-split halves + 2-way LDS reduction. Writes aTf/bTf[r][ks][khf][c][8s].
__global__ __launch_bounds__(256) void k_proj(const float* __restrict__ msa,
                                              const __bf16* __restrict__ WLRT,
                                              __bf16* __restrict__ aTf,
                                              __bf16* __restrict__ bTf) {
    __shared__ __align__(16) __bf16 As[32 * 256];       // 16 KB
    __shared__ __align__(16) char Pq[2 * 4096];         // 8 KB partials
    const int r = blockIdx.x;
    const int sq = blockIdx.y;                          // 0..3
    const int t = threadIdx.x;

#pragma unroll
    for (int it = 0; it < 8; ++it) {
        int idx = it * 256 + t;
        int row = idx >> 6;            // 0..31
        int cg = idx & 63;
        float4 v = *(const float4*)&msa[((size_t)(sq * 32 + row) * R + r) * CM + cg * 4];
        bf16x4 h = cvt4(v.x, v.y, v.z, v.w);
        int P = (cg >> 1) ^ (row & 15);
        *(bf16x4*)((char*)As + row * 512 + P * 16 + (cg & 1) * 8) = h;
    }
    __syncthreads();

    const int w = t >> 6;
    const int l = t & 63;
    const int l31 = t & 31;
    const int kh = (t >> 5) & 1;
    const int sd = w & 1;              // 0 = left, 1 = right
    const int ksh = w >> 1;            // m-half

    f32x16 acc;
#pragma unroll
    for (int q = 0; q < 16; ++q) acc[q] = 0.f;

    const bf16x8* wb = (const bf16x8*)&WLRT[(size_t)(sd * 32 + l31) * 256 + 8 * kh];
    const char* arow = (const char*)As + l31 * 512;

    __builtin_amdgcn_s_setprio(1);
#pragma unroll
    for (int j = 0; j < 8; ++j) {
        int ks = ksh * 8 + j;
        int P = (2 * ks + kh) ^ (l31 & 15);
        bf16x8 af = *(const bf16x8*)(arow + P * 16);
        acc = MFMA(af, wb[2 * ks], acc, 0, 0, 0);
    }
    __builtin_amdgcn_s_setprio(0);

    char* pbase = Pq + (size_t)sd * 4096;
    if (ksh == 1) {
#pragma unroll
        for (int pc = 0; pc < 4; ++pc) {
            f32x4 v;
            v[0] = acc[4 * pc + 0]; v[1] = acc[4 * pc + 1];
            v[2] = acc[4 * pc + 2]; v[3] = acc[4 * pc + 3];
            *(f32x4*)(pbase + ((pc * 64) + l) * 16) = v;
        }
    }
    __syncthreads();
    if (ksh == 0) {
#pragma unroll
        for (int pc = 0; pc < 4; ++pc) {
            f32x4 v = *(const f32x4*)(pbase + ((pc * 64) + l) * 16);
            acc[4 * pc + 0] += v[0]; acc[4 * pc + 1] += v[1];
            acc[4 * pc + 2] += v[2]; acc[4 * pc + 3] += v[3];
        }
        __bf16* dst = sd ? bTf : aTf;
#pragma unroll
        for (int q = 0; q < 4; ++q) {
            size_t base = (size_t)r * 4096 + (size_t)(2 * sq + (q >> 1)) * 512 +
                          (size_t)(q & 1) * 256 + (size_t)l31 * 8 + 4 * kh;
            *(bf16x4*)&dst[base] = cvt4(acc[4 * q + 0], acc[4 * q + 1],
                                        acc[4 * q + 2], acc[4 * q + 3]);
        }
    }
}

// K2: 1 block/CU (grid 256), 512 thr / 8 waves. Block = 8r x 32t panel,
// 8 tiles of 32 pairs, pipelined: A(i)->buf(i&1) || B(i-1) from buf(i^1).
// W (128 VGPR) and a (64 VGPR) are REGISTER-RESIDENT for the whole kernel;
// only b rolls (asm loads, consumed after vmcnt). 2 lgkm-only barriers/iter.
__global__ __launch_bounds__(512, 1) void k_main(const __bf16* __restrict__ aTf,
                                                 const __bf16* __restrict__ bTf,
                                                 const __bf16* __restrict__ WTf,
                                                 float* __restrict__ out) {
    __shared__ __align__(16) __bf16 Gs[2 * 32768];   // 2 x 64 KB G buffers
    __shared__ __align__(16) float Pp[4096];         // 16 KB partials

    const int t = threadIdx.x;
    const int w = t >> 6;              // 0..7
    const int l = t & 63;
    const int lane = l & 31;
    const int kh = l >> 5;
    const int r0 = blockIdx.x * 8;
    const int tbase = blockIdx.y * 32;

    const int rg = w & 3;              // phase A: a-row group (2 rows)
    const int tg = w >> 2;             // phase A: t-col group (2 cols)
    const int ng = w & 3;              // phase B: cz slice
    const int mh = w >> 2;             // phase B: K half

    // ---------------- Prologue: persistent register operands ----------------
    bf16x8 Aa[2][8];
    {
        const bf16x8* ap0 = (const bf16x8*)aTf + ((size_t)(r0 + 2 * rg + 0) * 512 + kh * 32 + lane);
        const bf16x8* ap1 = (const bf16x8*)aTf + ((size_t)(r0 + 2 * rg + 1) * 512 + kh * 32 + lane);
#pragma unroll
        for (int ks = 0; ks < 8; ++ks) { Aa[0][ks] = ap0[ks * 64]; Aa[1][ks] = ap1[ks * 64]; }
    }
    const int czl = ng * 32 + lane;
    bf16x8 Wp[32];
    {
        const bf16x8* wptr = (const bf16x8*)WTf + ((size_t)mh * 8192 + (size_t)kh * 128 + czl);
#pragma unroll
        for (int s = 0; s < 32; ++s) Wp[s] = wptr[(size_t)s * 256];
    }
    bf16x8 Bc[2][8];
    {
        const bf16x8* bq0 = (const bf16x8*)bTf + ((size_t)(tbase + 2 * tg + 0) * 512 + kh * 32 + lane);
        const bf16x8* bq1 = (const bf16x8*)bTf + ((size_t)(tbase + 2 * tg + 1) * 512 + kh * 32 + lane);
#pragma unroll
        for (int ks = 0; ks < 8; ++ks) { Bc[0][ks] = bq0[ks * 64]; Bc[1][ks] = bq1[ks * 64]; }
    }

    const unsigned prowG = (unsigned)lane * 2048;
    const int p15r = lane & 15;

#pragma unroll 1
    for (int i = 0; i <= 8; ++i) {
        char* gw = (char*)Gs + (size_t)(i & 1) * 65536;
        const char* gr = (const char*)Gs + (size_t)((i ^ 1) & 1) * 65536;

        // ---------------- Phase A: tile i -> gw ----------------
        if (i < 8) {
            asm volatile("s_waitcnt vmcnt(0)");           // b(i) (and stores) landed
            __builtin_amdgcn_sched_barrier(0);

            f32x16 acc[2][2];
#pragma unroll
            for (int ii = 0; ii < 2; ++ii)
#pragma unroll
                for (int jj = 0; jj < 2; ++jj)
#pragma unroll
                    for (int q = 0; q < 16; ++q) acc[ii][jj][q] = 0.f;

            const char* bn0 = (const char*)bTf +
                ((size_t)(tbase + 4 * (i + 1) + 2 * tg + 0) * 512 + kh * 32 + lane) * 16;
            const char* bn1 = (const char*)bTf +
                ((size_t)(tbase + 4 * (i + 1) + 2 * tg + 1) * 512 + kh * 32 + lane) * 16;

#pragma unroll
            for (int ks = 0; ks < 8; ++ks) {
                __builtin_amdgcn_s_setprio(1);
                acc[0][0] = MFMA(Aa[0][ks], Bc[0][ks], acc[0][0], 0, 0, 0);
                acc[0][1] = MFMA(Aa[0][ks], Bc[1][ks], acc[0][1], 0, 0, 0);
                acc[1][0] = MFMA(Aa[1][ks], Bc[0][ks], acc[1][0], 0, 0, 0);
                acc[1][1] = MFMA(Aa[1][ks], Bc[1][ks], acc[1][1], 0, 0, 0);
                __builtin_amdgcn_s_setprio(0);
                if (i + 1 < 8) {   // roll b(i+1) into the just-consumed slots
                    asm volatile("global_load_dwordx4 %0, %1, off"
                                 : "=v"(Bc[0][ks]) : "v"(bn0 + (size_t)ks * 1024));
                    asm volatile("global_load_dwordx4 %0, %1, off"
                                 : "=v"(Bc[1][ks]) : "v"(bn1 + (size_t)ks * 1024));
                }
            }

            // G-write (swizzled)
#pragma unroll
            for (int ii = 0; ii < 2; ++ii) {
#pragma unroll
                for (int jj = 0; jj < 2; ++jj) {
                    int p = (2 * rg + ii) * 4 + 2 * tg + jj;
                    unsigned prow = (unsigned)p * 2048;
#pragma unroll
                    for (int q = 0; q < 4; ++q) {
                        int Lc = lane * 4 + q;
                        int P = Lc ^ (p & 15) ^ (lane & 7);
                        *(bf16x4*)(gw + prow + (unsigned)P * 16 + kh * 8) =
                            cvt4(acc[ii][jj][4 * q + 0], acc[ii][jj][4 * q + 1],
                                 acc[ii][jj][4 * q + 2], acc[ii][jj][4 * q + 3]);
                    }
                }
            }
        }

        // ---------------- Phase B: tile i-1 from gr ----------------
        f32x16 oA, oB;
        if (i >= 1) {
#pragma unroll
            for (int q = 0; q < 16; ++q) { oA[q] = 0.f; oB[q] = 0.f; }

            bf16x8 Gp[4];
            const int kb = mh * 32;
#define LDG1(sl, ss) do { \
    int Lr = (kb + (ss)) * 2 + kh; \
    int P = Lr ^ p15r ^ ((Lr >> 2) & 7); \
    Gp[sl] = *(const bf16x8*)(gr + prowG + (unsigned)P * 16); } while (0)

            LDG1(0, 0); LDG1(1, 1); LDG1(2, 2); LDG1(3, 3);
#pragma unroll
            for (int s = 0; s < 32; ++s) {
                __builtin_amdgcn_s_setprio(1);
                if (s & 1) oB = MFMA(Gp[s & 3], Wp[s], oB, 0, 0, 0);
                else       oA = MFMA(Gp[s & 3], Wp[s], oA, 0, 0, 0);
                __builtin_amdgcn_s_setprio(0);
                if (s + 4 < 32) LDG1(s & 3, s + 4);
            }
        }

        asm volatile("s_waitcnt lgkmcnt(0)");
        __builtin_amdgcn_s_barrier();                   // #1: G(i) ready; B(i-1) reads done

        if (i >= 1) {
            f32x16 osum = oA + oB;
            if (mh == 1) {
                char* pb = (char*)Pp + (size_t)ng * 4096;
#pragma unroll
                for (int pc = 0; pc < 4; ++pc) {
                    f32x4 v;
                    v[0] = osum[4 * pc + 0]; v[1] = osum[4 * pc + 1];
                    v[2] = osum[4 * pc + 2]; v[3] = osum[4 * pc + 3];
                    *(f32x4*)(pb + (pc * 64 + l) * 16) = v;
                }
            }
            asm volatile("s_waitcnt lgkmcnt(0)");
            __builtin_amdgcn_s_barrier();               // #2: partials visible
            if (mh == 0) {
                const char* pb = (const char*)Pp + (size_t)ng * 4096;
#pragma unroll
                for (int pc = 0; pc < 4; ++pc) {
                    f32x4 v = *(const f32x4*)(pb + (pc * 64 + l) * 16);
                    osum[4 * pc + 0] += v[0]; osum[4 * pc + 1] += v[1];
                    osum[4 * pc + 2] += v[2]; osum[4 * pc + 3] += v[3];
                }
                const int tb2 = tbase + 4 * (i - 1);
#pragma unroll
                for (int reg = 0; reg < 16; ++reg) {
                    int pl = (reg & 3) + 8 * (reg >> 2) + 4 * kh;
                    int rl = pl >> 2, tl = pl & 3;
                    out[((size_t)(r0 + rl) * 256 + (tb2 + tl)) * 128 + czl] = osum[reg];
                }
            }
        }
    }
}

extern "C" void kernel_launch(void* const* d_in, const int* in_sizes, int n_in,
                              void* d_out, int out_size, void* d_ws, size_t ws_size,
                              hipStream_t stream) {
    const float* msa = (const float*)d_in[0];
    const float* left = (const float*)d_in[1];
    const float* right = (const float*)d_in[2];
    const float* W = (const float*)d_in[3];

    __bf16* aTf = (__bf16*)d_ws;                        // 2 MB
    __bf16* bTf = aTf + (size_t)R * 4096;               // 2 MB
    __bf16* WTf = bTf + (size_t)R * 4096;               // 256 KB
    __bf16* WLRT = WTf + (size_t)128 * 1024;            // 32 KB
    float* outp = (float*)d_out;

    k_prep<<<576, 256, 0, stream>>>(W, left, right, WTf, WLRT);
    k_proj<<<dim3(256, 4), 256, 0, stream>>>(msa, WLRT, aTf, bTf);
    k_main<<<dim3(32, 8), 512, 0, stream>>>(aTf, bTf, WTf, outp);
}

// Round 16
// 62.432 us; speedup vs baseline: 3.2816x; 3.2816x over previous
//
#include <hip/hip_runtime.h>

typedef __bf16 bf16x8 __attribute__((ext_vector_type(8)));
typedef __bf16 bf16x4 __attribute__((ext_vector_type(4)));
typedef float f32x16 __attribute__((ext_vector_type(16)));
typedef float f32x4 __attribute__((ext_vector_type(4)));

constexpr int S = 128, R = 256, CM = 256, C = 32, CZ = 128;

#define MFMA __builtin_amdgcn_mfma_f32_32x32x16_bf16

__device__ __forceinline__ bf16x4 cvt4(float a, float b, float c, float d) {
    bf16x4 r;
    r[0] = (__bf16)a; r[1] = (__bf16)b; r[2] = (__bf16)c; r[3] = (__bf16)d;
    return r;
}

// K0: merged prep. blocks 0..511: WTf[((k>>3)*128+cz)*8+(k&7)] = bf16(W[(c*32+e)*128+cz]);
// blocks 512..575: WLRT[c][m] from left/right.
__global__ __launch_bounds__(256) void k_prep(const float* __restrict__ W,
                                              const float* __restrict__ Lp,
                                              const float* __restrict__ Rp,
                                              __bf16* __restrict__ WTf,
                                              __bf16* __restrict__ WLRT) {
    int b = blockIdx.x;
    if (b < 512) {
        int g = b * 256 + threadIdx.x;
        int cz = g & 127;
        int k = g >> 7;
        int e = k >> 5, c = k & 31;
        float v = W[(size_t)(c * 32 + e) * 128 + cz];
        WTf[((size_t)(k >> 3) * 128 + cz) * 8 + (k & 7)] = (__bf16)v;
    } else {
        int c = b - 512;
        int m = threadIdx.x;
        const float* src = (c < 32) ? Lp : Rp;
        WLRT[(size_t)c * 256 + m] = (__bf16)src[(size_t)m * 32 + (c & 31)];
    }
}

// K1: block (r, s-quarter=32 rows), 256 thr / 4 waves = (ksh x sd).
// K(m)-split halves + 2-way LDS reduction. Writes aTf/bTf[r][ks][khf][c][8s].
__global__ __launch_bounds__(256) void k_proj(const float* __restrict__ msa,
                                              const __bf16* __restrict__ WLRT,
                                              __bf16* __restrict__ aTf,
                                              __bf16* __restrict__ bTf) {
    __shared__ __align__(16) __bf16 As[32 * 256];       // 16 KB
    __shared__ __align__(16) char Pp[2 * 4096];         // 8 KB partials
    const int r = blockIdx.x;
    const int sq = blockIdx.y;                          // 0..3
    const int t = threadIdx.x;

#pragma unroll
    for (int it = 0; it < 8; ++it) {
        int idx = it * 256 + t;
        int row = idx >> 6;            // 0..31
        int cg = idx & 63;
        float4 v = *(const float4*)&msa[((size_t)(sq * 32 + row) * R + r) * CM + cg * 4];
        bf16x4 h = cvt4(v.x, v.y, v.z, v.w);
        int P = (cg >> 1) ^ (row & 15);
        *(bf16x4*)((char*)As + row * 512 + P * 16 + (cg & 1) * 8) = h;
    }
    __syncthreads();

    const int w = t >> 6;
    const int l = t & 63;
    const int l31 = t & 31;
    const int kh = (t >> 5) & 1;
    const int sd = w & 1;              // 0 = left, 1 = right
    const int ksh = w >> 1;            // m-half

    f32x16 acc;
#pragma unroll
    for (int q = 0; q < 16; ++q) acc[q] = 0.f;

    const bf16x8* wb = (const bf16x8*)&WLRT[(size_t)(sd * 32 + l31) * 256 + 8 * kh];
    const char* arow = (const char*)As + l31 * 512;

    __builtin_amdgcn_s_setprio(1);
#pragma unroll
    for (int j = 0; j < 8; ++j) {
        int ks = ksh * 8 + j;
        int P = (2 * ks + kh) ^ (l31 & 15);
        bf16x8 af = *(const bf16x8*)(arow + P * 16);
        acc = MFMA(af, wb[2 * ks], acc, 0, 0, 0);
    }
    __builtin_amdgcn_s_setprio(0);

    char* pbase = Pp + (size_t)sd * 4096;
    if (ksh == 1) {
#pragma unroll
        for (int pc = 0; pc < 4; ++pc) {
            f32x4 v;
            v[0] = acc[4 * pc + 0]; v[1] = acc[4 * pc + 1];
            v[2] = acc[4 * pc + 2]; v[3] = acc[4 * pc + 3];
            *(f32x4*)(pbase + ((pc * 64) + l) * 16) = v;
        }
    }
    __syncthreads();
    if (ksh == 0) {
#pragma unroll
        for (int pc = 0; pc < 4; ++pc) {
            f32x4 v = *(const f32x4*)(pbase + ((pc * 64) + l) * 16);
            acc[4 * pc + 0] += v[0]; acc[4 * pc + 1] += v[1];
            acc[4 * pc + 2] += v[2]; acc[4 * pc + 3] += v[3];
        }
        __bf16* dst = sd ? bTf : aTf;
#pragma unroll
        for (int q = 0; q < 4; ++q) {
            size_t base = (size_t)r * 4096 + (size_t)(2 * sq + (q >> 1)) * 512 +
                          (size_t)(q & 1) * 256 + (size_t)l31 * 8 + 4 * kh;
            *(bf16x4*)&dst[base] = cvt4(acc[4 * q + 0], acc[4 * q + 1],
                                        acc[4 * q + 2], acc[4 * q + 3]);
        }
    }
}

// K2: 32 pairs (8r x 4t), 512 thr / 8 waves, 64 KB LDS, __launch_bounds__(512,4)
// -> VGPR<=128, 2 blocks/CU, 16 waves/CU (4/SIMD), blocks phase-decoupled.
// Phase A: wave (rg=w>>1, tg=w&1) -> 2r x 2t (acc[2][2]), depth-2 ping-pong.
// Phase B: wave (kq=w>>1, ng=w&1): 32-pair M-tile x 2 cz-slices over K-quarter,
// depth-2 ping-pong. 4-way K reduction via dead-G partials (48 KB <= 64 KB).
__global__ __launch_bounds__(512, 4) void k_main(const __bf16* __restrict__ aTf,
                                                 const __bf16* __restrict__ bTf,
                                                 const __bf16* __restrict__ WTf,
                                                 float* __restrict__ out) {
    __shared__ __align__(16) __bf16 Gs[32 * 1024];   // 64 KB

    const int t = threadIdx.x;
    const int w = t >> 6;              // 0..7
    const int l = t & 63;
    const int lane = l & 31;
    const int kh = l >> 5;
    const int r0 = blockIdx.x * 8;
    const int t0 = blockIdx.y * 4;

    // ---------------- Phase A ----------------
    const int rg = w >> 1;             // 0..3 (2 rows each)
    const int tg = w & 1;              // 0..1 (2 cols each)

    f32x16 acc[2][2];
#pragma unroll
    for (int i = 0; i < 2; ++i)
#pragma unroll
        for (int j = 0; j < 2; ++j)
#pragma unroll
            for (int q = 0; q < 16; ++q) acc[i][j][q] = 0.f;

    const bf16x8* ap0 = (const bf16x8*)aTf + ((size_t)(r0 + 2 * rg + 0) * 512 + kh * 32 + lane);
    const bf16x8* ap1 = (const bf16x8*)aTf + ((size_t)(r0 + 2 * rg + 1) * 512 + kh * 32 + lane);
    const bf16x8* bq0 = (const bf16x8*)bTf + ((size_t)(t0 + 2 * tg + 0) * 512 + kh * 32 + lane);
    const bf16x8* bq1 = (const bf16x8*)bTf + ((size_t)(t0 + 2 * tg + 1) * 512 + kh * 32 + lane);

    bf16x8 Ap[2][2], Bp[2][2];
#define LDA(s, ks) do { \
    Ap[s][0] = ap0[(ks) * 64]; Ap[s][1] = ap1[(ks) * 64]; \
    Bp[s][0] = bq0[(ks) * 64]; Bp[s][1] = bq1[(ks) * 64]; } while (0)
#define PH_A(s) do { \
    __builtin_amdgcn_s_setprio(1); \
    acc[0][0] = MFMA(Ap[s][0], Bp[s][0], acc[0][0], 0, 0, 0); \
    acc[0][1] = MFMA(Ap[s][0], Bp[s][1], acc[0][1], 0, 0, 0); \
    acc[1][0] = MFMA(Ap[s][1], Bp[s][0], acc[1][0], 0, 0, 0); \
    acc[1][1] = MFMA(Ap[s][1], Bp[s][1], acc[1][1], 0, 0, 0); \
    __builtin_amdgcn_s_setprio(0); } while (0)

    LDA(0, 0); LDA(1, 1);
#pragma unroll
    for (int ks = 0; ks < 8; ks += 2) {
        PH_A(0); LDA(0, (ks + 2) & 7);
        PH_A(1); LDA(1, (ks + 3) & 7);
    }

    // G -> LDS, row p = (2rg+ii)*4 + 2tg+jj (2048 B), chunk swizzle
#pragma unroll
    for (int i = 0; i < 2; ++i) {
#pragma unroll
        for (int j = 0; j < 2; ++j) {
            int p = (2 * rg + i) * 4 + 2 * tg + j;
            unsigned prow = (unsigned)p * 2048;
#pragma unroll
            for (int q = 0; q < 4; ++q) {
                int Lc = lane * 4 + q;
                int P = Lc ^ (p & 15) ^ (lane & 7);
                *(bf16x4*)((char*)Gs + prow + (unsigned)P * 16 + kh * 8) =
                    cvt4(acc[i][j][4 * q + 0], acc[i][j][4 * q + 1],
                         acc[i][j][4 * q + 2], acc[i][j][4 * q + 3]);
            }
        }
    }
    __syncthreads();

    // ---------------- Phase B ----------------
    const int kq = w >> 1;             // K-quarter 0..3
    const int ng = w & 1;              // cz pair-group
    const int czl0 = ng * 64 + lane;
    const int czl1 = czl0 + 32;
    const bf16x8* wb0 = (const bf16x8*)WTf + ((size_t)kh * 128 + czl0);
    const bf16x8* wb1 = (const bf16x8*)WTf + ((size_t)kh * 128 + czl1);
    const unsigned prowG = (unsigned)lane * 2048;
    const int p15 = lane & 15;

    f32x16 o0, o1;
#pragma unroll
    for (int q = 0; q < 16; ++q) { o0[q] = 0.f; o1[q] = 0.f; }

    bf16x8 Wa0, Wa1, Ga, Wb0_, Wb1_, Gb;
#define LDB(W0v, W1v, Gv, kk) do { \
    W0v = wb0[(size_t)(kk) * 256]; \
    W1v = wb1[(size_t)(kk) * 256]; \
    int Lr = (kk) * 2 + kh; \
    int P = Lr ^ p15 ^ ((Lr >> 2) & 7); \
    Gv = *(const bf16x8*)((const char*)Gs + prowG + (unsigned)P * 16); } while (0)
#define PHB(W0v, W1v, Gv) do { \
    __builtin_amdgcn_s_setprio(1); \
    o0 = MFMA(Gv, W0v, o0, 0, 0, 0); \
    o1 = MFMA(Gv, W1v, o1, 0, 0, 0); \
    __builtin_amdgcn_s_setprio(0); } while (0)

    LDB(Wa0, Wa1, Ga, kq * 16);
#pragma unroll
    for (int j = 0; j < 16; j += 2) {
        LDB(Wb0_, Wb1_, Gb, kq * 16 + ((j + 1) & 15));
        PHB(Wa0, Wa1, Ga);
        LDB(Wa0, Wa1, Ga, kq * 16 + ((j + 2) & 15));
        PHB(Wb0_, Wb1_, Gb);
    }
    __syncthreads();   // all G reads done; region reusable for partials

    // partials: region ((kq-1)*2+ng)*8 KB, layout [oi][pc][l] x 16B
    if (kq > 0) {
        char* pr = (char*)Gs + (size_t)((kq - 1) * 2 + ng) * 8192;
#pragma unroll
        for (int oi = 0; oi < 2; ++oi) {
            const f32x16& ov = oi ? o1 : o0;
#pragma unroll
            for (int pc = 0; pc < 4; ++pc) {
                f32x4 v;
                v[0] = ov[4 * pc + 0]; v[1] = ov[4 * pc + 1];
                v[2] = ov[4 * pc + 2]; v[3] = ov[4 * pc + 3];
                *(f32x4*)(pr + ((oi * 4 + pc) * 64 + l) * 16) = v;
            }
        }
    }
    __syncthreads();

    if (kq == 0) {
#pragma unroll
        for (int kq2 = 1; kq2 < 4; ++kq2) {
            const char* pr = (const char*)Gs + (size_t)((kq2 - 1) * 2 + ng) * 8192;
#pragma unroll
            for (int pc = 0; pc < 4; ++pc) {
                f32x4 v0 = *(const f32x4*)(pr + ((pc) * 64 + l) * 16);
                f32x4 v1 = *(const f32x4*)(pr + ((4 + pc) * 64 + l) * 16);
                o0[4 * pc + 0] += v0[0]; o0[4 * pc + 1] += v0[1];
                o0[4 * pc + 2] += v0[2]; o0[4 * pc + 3] += v0[3];
                o1[4 * pc + 0] += v1[0]; o1[4 * pc + 1] += v1[1];
                o1[4 * pc + 2] += v1[2]; o1[4 * pc + 3] += v1[3];
            }
        }
#pragma unroll
        for (int reg = 0; reg < 16; ++reg) {
            int pl = (reg & 3) + 8 * (reg >> 2) + 4 * kh;   // pair 0..31
            int pr2 = pl >> 2, pt = pl & 3;
            out[((size_t)(r0 + pr2) * 256 + (t0 + pt)) * 128 + czl0] = o0[reg];
            out[((size_t)(r0 + pr2) * 256 + (t0 + pt)) * 128 + czl1] = o1[reg];
        }
    }
}

extern "C" void kernel_launch(void* const* d_in, const int* in_sizes, int n_in,
                              void* d_out, int out_size, void* d_ws, size_t ws_size,
                              hipStream_t stream) {
    const float* msa = (const float*)d_in[0];
    const float* left = (const float*)d_in[1];
    const float* right = (const float*)d_in[2];
    const float* W = (const float*)d_in[3];

    __bf16* aTf = (__bf16*)d_ws;                        // 2 MB
    __bf16* bTf = aTf + (size_t)R * 4096;               // 2 MB
    __bf16* WTf = bTf + (size_t)R * 4096;               // 256 KB
    __bf16* WLRT = WTf + (size_t)128 * 1024;            // 32 KB
    float* outp = (float*)d_out;

    k_prep<<<576, 256, 0, stream>>>(W, left, right, WTf, WLRT);
    k_proj<<<dim3(256, 4), 256, 0, stream>>>(msa, WLRT, aTf, bTf);
    k_main<<<dim3(32, 64), 512, 0, stream>>>(aTf, bTf, WTf, outp);
}